// Round 6
// baseline (563.478 us; speedup 1.0000x reference)
//
#include <hip/hip_runtime.h>

#define NN 2048
#define CC 128
#define CPC 16
#define HH 8
#define DD 16
#define WHALF 64

__device__ __forceinline__ float sigf(float x){ return 1.0f/(1.0f+__expf(-x)); }

// 8-row x 128-col GEMM pass: thread covers row r=t>>5, cols c..c+3.
// X is an LDS tile [8][KK]; W0/W1 global [KK][ldw].
template<int KK, int NM, bool SC>
__device__ __forceinline__ void gemm_lds(const float* __restrict__ X,
    const float* __restrict__ scv,
    const float* __restrict__ W0, const float* __restrict__ W1,
    int ldw, int colBase, float a0[4], float a1[4]){
  const int t = threadIdx.x;
  const int r = t>>5;
  const int c = colBase + (t&31)*4;
  a0[0]=a0[1]=a0[2]=a0[3]=0.f;
  a1[0]=a1[1]=a1[2]=a1[3]=0.f;
  #pragma unroll 8
  for (int k=0;k<KK;k++){
    float a = X[r*KK+k];                 // 2-addr broadcast per wave: free
    if constexpr (SC) a *= scv[k];
    float4 w0 = *(const float4*)(W0 + (size_t)k*ldw + c);
    a0[0]+=a*w0.x; a0[1]+=a*w0.y; a0[2]+=a*w0.z; a0[3]+=a*w0.w;
    if constexpr (NM>1){
      float4 w1 = *(const float4*)(W1 + (size_t)k*ldw + c);
      a1[0]+=a*w1.x; a1[1]+=a*w1.y; a1[2]+=a*w1.z; a1[3]+=a*w1.w;
    }
  }
}

// Same but X row comes from global memory (same-address broadcast per 32-lane group).
template<int KK>
__device__ __forceinline__ void gemm_g(const float* __restrict__ Xrow,
    const float* __restrict__ W0, int ldw, float a0[4]){
  const int c = (threadIdx.x&31)*4;
  a0[0]=a0[1]=a0[2]=a0[3]=0.f;
  #pragma unroll 8
  for (int k=0;k<KK;k++){
    float a = Xrow[k];
    float4 w0 = *(const float4*)(W0 + (size_t)k*ldw + c);
    a0[0]+=a*w0.x; a0[1]+=a*w0.y; a0[2]+=a*w0.z; a0[3]+=a*w0.w;
  }
}

// LN over one 128-col row held as float4/thread across 32 lanes; returns normalized, raw via ref.
__device__ __forceinline__ float4 ln_row4(const float* __restrict__ x, int row, int c4, float4& raw){
  float4 v = *(const float4*)(x + (size_t)row*CC + c4);
  raw = v;
  float sm = v.x+v.y+v.z+v.w;
  float sq = v.x*v.x+v.y*v.y+v.z*v.z+v.w*v.w;
  #pragma unroll
  for (int m=16;m;m>>=1){ sm += __shfl_xor(sm,m); sq += __shfl_xor(sq,m); }
  float mean = sm*(1.0f/CC);
  float var  = sq*(1.0f/CC)-mean*mean;
  float inv  = rsqrtf(var+1e-5f);
  float4 o; o.x=(v.x-mean)*inv; o.y=(v.y-mean)*inv; o.z=(v.z-mean)*inv; o.w=(v.w-mean)*inv;
  return o;
}

// MEGA1: per 8-row tile. y=0: out-gates + AdaLN#1 + q/k/v/g. y=1: AdaLN#2 + SwiGLU.
__global__ __launch_bounds__(256) void mega1(
    const float* __restrict__ a_in, const float* __restrict__ s_in,
    const float* __restrict__ sc1, const float* __restrict__ gw,
    const float* __restrict__ gb,  const float* __restrict__ skw,
    const float* __restrict__ ogw, const float* __restrict__ ogb,
    const float* __restrict__ ogw2,const float* __restrict__ ogb2,
    const float* __restrict__ wq, const float* __restrict__ wk,
    const float* __restrict__ wv, const float* __restrict__ wg,
    const float* __restrict__ bg,
    const float* __restrict__ sc2, const float* __restrict__ tgw,
    const float* __restrict__ tgb, const float* __restrict__ tskw,
    const float* __restrict__ sww, const float* __restrict__ hdw,
    float* __restrict__ qb, float* __restrict__ kb,
    float* __restrict__ vb, float* __restrict__ gg,
    float* __restrict__ sgog, float* __restrict__ sgtg,
    float* __restrict__ hid){
  __shared__ float ls[8*128];     // ln_s tile
  __shared__ float la[8*128];     // ln_a tile
  __shared__ float aux[8*128];    // raw s (y0) / unused (y1)
  __shared__ float xbuf[8*128];   // a_att (y0) / tcond (y1)
  __shared__ float scv[128];
  const int t = threadIdx.x;
  const int row0 = blockIdx.x*8;
  const int y = blockIdx.y;
  const int r = t>>5;
  const int c4 = (t&31)*4;
  const int row = row0 + r;
  {
    float4 raw;
    float4 n = ln_row4(s_in, row, c4, raw);
    *(float4*)(ls + r*128 + c4) = n;
    if (y==0) *(float4*)(aux + r*128 + c4) = raw;
  }
  {
    float4 raw;
    float4 n = ln_row4(a_in, row, c4, raw);
    *(float4*)(la + r*128 + c4) = n;
  }
  if (t < 128) scv[t] = (y==0 ? sc1 : sc2)[t];
  __syncthreads();

  float p0[4], p1[4];
  if (y==0){
    // P1: output gates from raw s (post-sigmoid stored)
    gemm_lds<128,2,false>(aux, nullptr, ogw, ogw2, 128, 0, p0, p1);
    {
      float4 b0 = *(const float4*)(ogb + c4);
      float4 b1 = *(const float4*)(ogb2 + c4);
      float4 o0 = { sigf(p0[0]+b0.x), sigf(p0[1]+b0.y), sigf(p0[2]+b0.z), sigf(p0[3]+b0.w) };
      float4 o1 = { sigf(p1[0]+b1.x), sigf(p1[1]+b1.y), sigf(p1[2]+b1.z), sigf(p1[3]+b1.w) };
      *(float4*)(sgog + (size_t)row*CC + c4) = o0;
      *(float4*)(sgtg + (size_t)row*CC + c4) = o1;
    }
    // P2: AdaLN#1 -> xbuf
    gemm_lds<128,2,true>(ls, scv, gw, skw, 128, 0, p0, p1);
    {
      float4 gbv = *(const float4*)(gb + c4);
      float4 lav = *(const float4*)(la + r*128 + c4);
      float4 o;
      o.x = sigf(p0[0]+gbv.x)*lav.x + p1[0];
      o.y = sigf(p0[1]+gbv.y)*lav.y + p1[1];
      o.z = sigf(p0[2]+gbv.z)*lav.z + p1[2];
      o.w = sigf(p0[3]+gbv.w)*lav.w + p1[3];
      *(float4*)(xbuf + r*128 + c4) = o;
    }
    __syncthreads();
    // P3: q,k
    gemm_lds<128,2,false>(xbuf, nullptr, wq, wk, 128, 0, p0, p1);
    *(float4*)(qb + (size_t)row*CC + c4) = *(float4*)p0;
    *(float4*)(kb + (size_t)row*CC + c4) = *(float4*)p1;
    // P4: v,g (+bg, pre-sigmoid)
    gemm_lds<128,2,false>(xbuf, nullptr, wv, wg, 128, 0, p0, p1);
    {
      float4 bgv = *(const float4*)(bg + c4);
      float4 o1 = { p1[0]+bgv.x, p1[1]+bgv.y, p1[2]+bgv.z, p1[3]+bgv.w };
      *(float4*)(vb + (size_t)row*CC + c4) = *(float4*)p0;
      *(float4*)(gg + (size_t)row*CC + c4) = o1;
    }
  } else {
    // P5: AdaLN#2 -> xbuf (tcond)
    gemm_lds<128,2,true>(ls, scv, tgw, tskw, 128, 0, p0, p1);
    {
      float4 gbv = *(const float4*)(tgb + c4);
      float4 lav = *(const float4*)(la + r*128 + c4);
      float4 o;
      o.x = sigf(p0[0]+gbv.x)*lav.x + p1[0];
      o.y = sigf(p0[1]+gbv.y)*lav.y + p1[1];
      o.z = sigf(p0[2]+gbv.z)*lav.z + p1[2];
      o.w = sigf(p0[3]+gbv.w)*lav.w + p1[3];
      *(float4*)(xbuf + r*128 + c4) = o;
    }
    __syncthreads();
    // P6/P7: SwiGLU halves -> hid [NN][256]
    #pragma unroll
    for (int cb=0; cb<256; cb+=128){
      gemm_lds<128,2,false>(xbuf, nullptr, sww, hdw, 256, cb, p0, p1);
      float4 o;
      o.x = p0[0]*sigf(p0[0])*p1[0];
      o.y = p0[1]*sigf(p0[1])*p1[1];
      o.z = p0[2]*sigf(p0[2])*p1[2];
      o.w = p0[3]*sigf(p0[3])*p1[3];
      *(float4*)(hid + (size_t)row*256 + cb + c4) = o;
    }
  }
}

// MEGA2: out = sg_og*(o_gat@wo + bo) + sg_tg*(hid@t_out_w)
__global__ __launch_bounds__(256) void mega2(const float* __restrict__ o_gat,
    const float* __restrict__ hid, const float* __restrict__ wo,
    const float* __restrict__ bo, const float* __restrict__ tow,
    const float* __restrict__ sgog, const float* __restrict__ sgtg,
    float* __restrict__ outp){
  const int t = threadIdx.x;
  const int row = blockIdx.x*8 + (t>>5);
  const int c4 = (t&31)*4;
  float ao[4], tr[4];
  gemm_g<128>(o_gat + (size_t)row*CC, wo, 128, ao);
  gemm_g<256>(hid + (size_t)row*256, tow, 128, tr);
  float4 bb = *(const float4*)(bo + c4);
  float4 g0 = *(const float4*)(sgog + (size_t)row*CC + c4);
  float4 g1 = *(const float4*)(sgtg + (size_t)row*CC + c4);
  float4 o;
  o.x = g0.x*(ao[0]+bb.x) + g1.x*tr[0];
  o.y = g0.y*(ao[1]+bb.y) + g1.y*tr[1];
  o.z = g0.z*(ao[2]+bb.z) + g1.z*tr[2];
  o.w = g0.w*(ao[3]+bb.w) + g1.w*tr[3];
  *(float4*)(outp + (size_t)row*CC + c4) = o;
}

// Windowed attention with pair bias. One block per query row i. 256 threads.
__global__ __launch_bounds__(256) void attn_win(const float* __restrict__ q,
    const float* __restrict__ k, const float* __restrict__ v,
    const float* __restrict__ g, const float* __restrict__ pair,
    const float* __restrict__ pls, const float* __restrict__ plb,
    const float* __restrict__ w_pair, const float* __restrict__ mask,
    float* __restrict__ o_out) {
  __shared__ __align__(16) float qs[CC];
  __shared__ float sc[HH][132];
  __shared__ float wp[CPC][HH];
  __shared__ float plss[CPC], plbs[CPC];
  __shared__ float inv_sum[HH];
  const int i = blockIdx.x;
  const int t = threadIdx.x;
  if (t < CC) qs[t] = q[(size_t)i*CC + t] * 0.25f;   // D^-0.5 = 1/4
  if (t < CPC*HH) wp[t>>3][t&7] = w_pair[t];         // [CP][H] row-major
  if (t >= 128 && t < 128+CPC){ plss[t-128]=pls[t-128]; plbs[t-128]=plb[t-128]; }
  __syncthreads();
  const int jlo = (i-WHALF > 0) ? i-WHALF : 0;
  const int jhi = (i+WHALF < NN-1) ? i+WHALF : NN-1;
  const int nj = jhi - jlo + 1;      // 65..129
  if (t < nj){
    const int j = jlo + t;
    float pv[CPC]; float s=0.f, sq=0.f;
    const float4* pp4 = (const float4*)(pair + ((size_t)i*NN + j)*CPC);
    #pragma unroll
    for (int c4=0;c4<CPC/4;c4++){
      float4 x4 = pp4[c4];
      pv[c4*4]=x4.x; pv[c4*4+1]=x4.y; pv[c4*4+2]=x4.z; pv[c4*4+3]=x4.w;
      s += x4.x+x4.y+x4.z+x4.w;
      sq += x4.x*x4.x+x4.y*x4.y+x4.z*x4.z+x4.w*x4.w;
    }
    float mean = s*(1.0f/CPC);
    float var  = sq*(1.0f/CPC)-mean*mean;
    float inv  = rsqrtf(var+1e-5f);
    #pragma unroll
    for (int c=0;c<CPC;c++) pv[c] = (pv[c]-mean)*inv*plss[c] + plbs[c];
    float mterm = 1e9f*(mask[j]-1.0f);
    const float4* kr4 = (const float4*)(k + (size_t)j*CC);
    const float4* qs4 = (const float4*)qs;
    #pragma unroll
    for (int h=0;h<HH;h++){
      float bias = 0.f;
      #pragma unroll
      for (int c=0;c<CPC;c++) bias += pv[c]*wp[c][h];
      float d = 0.f;
      #pragma unroll
      for (int w=0;w<4;w++){
        float4 kk = kr4[h*4+w];
        float4 qq = qs4[h*4+w];
        d += kk.x*qq.x + kk.y*qq.y + kk.z*qq.z + kk.w*qq.w;
      }
      sc[h][t] = d + bias + mterm;
    }
  }
  __syncthreads();
  { // per-head softmax: 8 groups of 32 lanes
    const int h = t >> 5;
    const int l = t & 31;
    float m = -1e30f;
    for (int jj=l; jj<nj; jj+=32) m = fmaxf(m, sc[h][jj]);
    #pragma unroll
    for (int mm=16;mm;mm>>=1) m = fmaxf(m, __shfl_xor(m,mm));
    float ss = 0.f;
    for (int jj=l; jj<nj; jj+=32){ float e=__expf(sc[h][jj]-m); sc[h][jj]=e; ss+=e; }
    #pragma unroll
    for (int mm=16;mm;mm>>=1) ss += __shfl_xor(ss,mm);
    if (l==0) inv_sum[h] = 1.0f/ss;
  }
  __syncthreads();
  if (t < CC){
    const int h = t >> 4;
    const float* vt = v + t;
    float a0=0.f,a1=0.f,a2=0.f,a3=0.f;
    int jj=0;
    for (; jj+4<=nj; jj+=4){
      a0 += sc[h][jj]   * vt[(size_t)(jlo+jj)*CC];
      a1 += sc[h][jj+1] * vt[(size_t)(jlo+jj+1)*CC];
      a2 += sc[h][jj+2] * vt[(size_t)(jlo+jj+2)*CC];
      a3 += sc[h][jj+3] * vt[(size_t)(jlo+jj+3)*CC];
    }
    for (; jj<nj; jj++) a0 += sc[h][jj]*vt[(size_t)(jlo+jj)*CC];
    float acc = (a0+a1)+(a2+a3);
    float gate = sigf(g[(size_t)i*CC + t]);
    o_out[(size_t)i*CC + t] = acc * inv_sum[h] * gate;
  }
}

extern "C" void kernel_launch(void* const* d_in, const int* in_sizes, int n_in,
                              void* d_out, int out_size, void* d_ws, size_t ws_size,
                              hipStream_t stream) {
  const float* a_in = (const float*)d_in[0];
  const float* s_in = (const float*)d_in[1];
  const float* pair = (const float*)d_in[2];
  const float* mask = (const float*)d_in[3];
  const float* adaln_s_scale = (const float*)d_in[4];
  const float* adaln_gate_w  = (const float*)d_in[5];
  const float* adaln_gate_b  = (const float*)d_in[6];
  const float* adaln_skip_w  = (const float*)d_in[7];
  const float* wq = (const float*)d_in[8];
  const float* wk = (const float*)d_in[9];
  const float* wv = (const float*)d_in[10];
  const float* wg = (const float*)d_in[11];
  const float* bg = (const float*)d_in[12];
  const float* wo = (const float*)d_in[13];
  const float* bo = (const float*)d_in[14];
  const float* pls = (const float*)d_in[15];
  const float* plb = (const float*)d_in[16];
  const float* w_pair = (const float*)d_in[17];
  const float* out_gate_w = (const float*)d_in[18];
  const float* out_gate_b = (const float*)d_in[19];
  const float* t_s_scale  = (const float*)d_in[20];
  const float* t_gate_w   = (const float*)d_in[21];
  const float* t_gate_b   = (const float*)d_in[22];
  const float* t_skip_w   = (const float*)d_in[23];
  const float* t_swish_w  = (const float*)d_in[24];
  const float* t_hidden_w = (const float*)d_in[25];
  const float* t_out_w    = (const float*)d_in[26];
  const float* t_out_gate_w = (const float*)d_in[27];
  const float* t_out_gate_b = (const float*)d_in[28];

  float* ws = (float*)d_ws;
  const size_t U = (size_t)NN*CC;
  float* qb    = ws + 0*U;
  float* kb    = ws + 1*U;
  float* vb    = ws + 2*U;
  float* gg    = ws + 3*U;
  float* sg_og = ws + 4*U;
  float* sg_tg = ws + 5*U;
  float* o_gat = ws + 6*U;
  float* hid   = ws + 7*U;   // 2 units [NN][256]

  dim3 blk(256);
  mega1<<<dim3(NN/8,2), blk, 0, stream>>>(a_in, s_in,
      adaln_s_scale, adaln_gate_w, adaln_gate_b, adaln_skip_w,
      out_gate_w, out_gate_b, t_out_gate_w, t_out_gate_b,
      wq, wk, wv, wg, bg,
      t_s_scale, t_gate_w, t_gate_b, t_skip_w,
      t_swish_w, t_hidden_w,
      qb, kb, vb, gg, sg_og, sg_tg, hid);
  attn_win<<<NN, blk, 0, stream>>>(qb, kb, vb, gg, pair, pls, plb, w_pair, mask, o_gat);
  mega2<<<NN/8, blk, 0, stream>>>(o_gat, hid, wo, bo, t_out_w, sg_og, sg_tg, (float*)d_out);
}